// Round 5
// baseline (407.677 us; speedup 1.0000x reference)
//
#include <hip/hip_runtime.h>
#include <hip/hip_bf16.h>

#define NPOS (384*384)
#define JDIM 384
#define CDIM 128
#define HNUM 4
#define DHD  32
#define LOG2E 1.4426950408889634f

typedef __attribute__((ext_vector_type(8))) short short8;
typedef __attribute__((ext_vector_type(4))) float floatx4;
typedef unsigned short ushort_t;

#if defined(__has_builtin)
#if __has_builtin(__builtin_amdgcn_exp2f)
#define EXP2F(x) __builtin_amdgcn_exp2f(x)
#endif
#endif
#ifndef EXP2F
#define EXP2F(x) __expf((x) * 0.6931471805599453f)
#endif

__device__ __forceinline__ float bf2f(unsigned short u){
  unsigned int x = ((unsigned int)u) << 16;
  return __builtin_bit_cast(float, x);
}
__device__ __forceinline__ unsigned short f2bf(float f){
  unsigned int u = __builtin_bit_cast(unsigned int, f);
  u = u + 0x7FFFu + ((u >> 16) & 1u);   // round-nearest-even
  return (unsigned short)(u >> 16);
}
// RNE-round two fp32 to bf16 and pack into one u32 (lo=a, hi=b)
__device__ __forceinline__ unsigned int pack2bf(float a, float b){
  unsigned int ua = __builtin_bit_cast(unsigned int, a);
  unsigned int ub = __builtin_bit_cast(unsigned int, b);
  ua = ua + 0x7FFFu + ((ua >> 16) & 1u);
  ub = ub + 0x7FFFu + ((ub >> 16) & 1u);
  return __builtin_amdgcn_perm(ub, ua, 0x07060302);  // [a.hi16, b.hi16]
}

// ---------------- weight transpose + cast: W[c][f] fp32 -> Wt[f][c] bf16 ----------------
__global__ __launch_bounds__(256) void wt_kernel(
    const float* wq, const float* wk, const float* wv,
    const float* wg, const float* wo, ushort_t* __restrict__ wt)
{
  int mat = blockIdx.x >> 6;
  int idx = ((blockIdx.x & 63) << 8) | threadIdx.x;
  const float* src = (mat==0)?wq:(mat==1)?wk:(mat==2)?wv:(mat==3)?wg:wo;
  int f = idx >> 7, c = idx & 127;
  wt[mat*16384 + idx] = f2bf(src[c*128 + f]);
}

// ---------------- fused LN + 128x128x128 MFMA projection ----------------
// grid (1152, 4): y = proj (0=q 1=k 2=v 3=g). LN done in-block from x; xn never
// hits HBM. y==0 blocks also emit tri (permuted pair layout, pre-scaled LOG2E).
__global__ __launch_bounds__(256, 2) void proj_fused_kernel(
    const float* __restrict__ x, const float* __restrict__ lnw,
    const float* __restrict__ lnb, const float* __restrict__ wtri,
    const ushort_t* __restrict__ wt, ushort_t* __restrict__ outb,
    const float* __restrict__ bg, float* __restrict__ trip2)
{
  __shared__ __align__(16) ushort_t As[128*144];
  __shared__ __align__(16) ushort_t Bs[128*144];
  int t = threadIdx.x;
  int proj = blockIdx.y;
  int row0 = blockIdx.x * 128;
  // THE ROUND-4 BUG: this offset was missing — all 4 projections wrote to qb.
  ushort_t* outp = outb + (size_t)proj * NPOS * CDIM;

  // stage B tile (weights, already transposed)
  const ushort_t* W = wt + proj*16384;
  #pragma unroll
  for (int i = 0; i < 8; i++){
    int v = t + i*256;
    int row = v >> 4, c8 = v & 15;
    *(short8*)(Bs + row*144 + c8*8) = *(const short8*)(W + v*8);
  }

  // LayerNorm: thread owns half a row (64 channels)
  int row = t >> 1, ch0 = (t & 1) * 64;
  const float* xr = x + (size_t)(row0 + row)*CDIM + ch0;
  float xv[64];
  float s = 0.f, ss = 0.f;
  #pragma unroll
  for (int c4 = 0; c4 < 16; c4++){
    float4 f4 = *(const float4*)(xr + c4*4);
    xv[c4*4+0]=f4.x; xv[c4*4+1]=f4.y; xv[c4*4+2]=f4.z; xv[c4*4+3]=f4.w;
    s += f4.x+f4.y+f4.z+f4.w;
    ss += f4.x*f4.x+f4.y*f4.y+f4.z*f4.z+f4.w*f4.w;
  }
  s += __shfl_xor(s, 1); ss += __shfl_xor(ss, 1);
  float mu = s*(1.0f/128.0f);
  float var = ss*(1.0f/128.0f) - mu*mu;
  float rstd = rsqrtf(var + 1e-5f);
  float t0=0.f, t1=0.f, t2=0.f, t3=0.f;
  #pragma unroll
  for (int c4 = 0; c4 < 16; c4++){
    float4 w4 = *(const float4*)(lnw + ch0 + c4*4);
    float4 b4 = *(const float4*)(lnb + ch0 + c4*4);
    float n0 = (xv[c4*4+0]-mu)*rstd*w4.x + b4.x;
    float n1 = (xv[c4*4+1]-mu)*rstd*w4.y + b4.y;
    float n2 = (xv[c4*4+2]-mu)*rstd*w4.z + b4.z;
    float n3 = (xv[c4*4+3]-mu)*rstd*w4.w + b4.w;
    ushort4 o4; o4.x=f2bf(n0); o4.y=f2bf(n1); o4.z=f2bf(n2); o4.w=f2bf(n3);
    *(ushort4*)(As + row*144 + ch0 + c4*4) = o4;
    if (proj == 0){
      const float* wtb = wtri + (ch0 + c4*4)*4;
      float4 wt0 = *(const float4*)(wtb);
      float4 wt1 = *(const float4*)(wtb + 4);
      float4 wt2 = *(const float4*)(wtb + 8);
      float4 wt3 = *(const float4*)(wtb + 12);
      t0 += n0*wt0.x + n1*wt1.x + n2*wt2.x + n3*wt3.x;
      t1 += n0*wt0.y + n1*wt1.y + n2*wt2.y + n3*wt3.y;
      t2 += n0*wt0.z + n1*wt1.z + n2*wt2.z + n3*wt3.z;
      t3 += n0*wt0.w + n1*wt1.w + n2*wt2.w + n3*wt3.w;
    }
  }
  if (proj == 0){
    t0 += __shfl_xor(t0,1); t1 += __shfl_xor(t1,1);
    t2 += __shfl_xor(t2,1); t3 += __shfl_xor(t3,1);
    if ((t & 1) == 0){
      int p = row0 + row;
      int ii = p / JDIM, j = p - ii*JDIM;
      int jp = (j & ~31) | ((j & 15) << 1) | ((j & 31) >> 4);  // V/P permutation
      size_t base = (size_t)ii*JDIM + jp;
      trip2[0*NPOS + base] = t0 * LOG2E;
      trip2[1*NPOS + base] = t1 * LOG2E;
      trip2[2*NPOS + base] = t2 * LOG2E;
      trip2[3*NPOS + base] = t3 * LOG2E;
    }
  }
  __syncthreads();

  int w = t >> 6, lane = t & 63;
  int wm = (w & 1) * 64, wn = (w >> 1) * 64;
  int m = lane & 15, q4 = lane >> 4;
  floatx4 acc[4][4];
  #pragma unroll
  for (int mi = 0; mi < 4; mi++)
    #pragma unroll
    for (int ni = 0; ni < 4; ni++)
      acc[mi][ni] = (floatx4){0.f, 0.f, 0.f, 0.f};
  #pragma unroll
  for (int k0 = 0; k0 < 128; k0 += 32){
    int koff = k0 + q4*8;
    short8 af[4], bf[4];
    #pragma unroll
    for (int mi = 0; mi < 4; mi++) af[mi] = *(const short8*)(As + (wm + mi*16 + m)*144 + koff);
    #pragma unroll
    for (int ni = 0; ni < 4; ni++) bf[ni] = *(const short8*)(Bs + (wn + ni*16 + m)*144 + koff);
    #pragma unroll
    for (int mi = 0; mi < 4; mi++)
      #pragma unroll
      for (int ni = 0; ni < 4; ni++)
        acc[mi][ni] = __builtin_amdgcn_mfma_f32_16x16x32_bf16(af[mi], bf[ni], acc[mi][ni], 0, 0, 0);
  }
  // q gets log2e/sqrt(32) so attention scores live in exp2 domain
  const float qscale = 0.17677669529663687f * LOG2E;
  #pragma unroll
  for (int mi = 0; mi < 4; mi++){
    #pragma unroll
    for (int ni = 0; ni < 4; ni++){
      int col = wn + ni*16 + m;
      float bv = (proj == 3) ? bg[col] : 0.f;
      #pragma unroll
      for (int r = 0; r < 4; r++){
        float val = acc[mi][ni][r];
        if (proj == 0) val *= qscale;
        else if (proj == 3) val = 1.f / (1.f + __expf(-(val + bv)));
        int orow = wm + mi*16 + q4*4 + r;
        outp[(size_t)(row0+orow)*CDIM + col] = f2bf(val);
      }
    }
  }
}

// ---------------- output GEMM: og[N,128] x wo^T + bo -> fp32 out ----------------
__global__ __launch_bounds__(256) void out_gemm_kernel(
    const ushort_t* __restrict__ og, const ushort_t* __restrict__ wt,
    float* __restrict__ out, const float* __restrict__ bo)
{
  __shared__ __align__(16) ushort_t As[128*144];
  __shared__ __align__(16) ushort_t Bs[128*144];
  int t = threadIdx.x;
  int row0 = blockIdx.x * 128;
  #pragma unroll
  for (int i = 0; i < 8; i++){
    int v = t + i*256;
    int row = v >> 4, c8 = v & 15;
    *(short8*)(As + row*144 + c8*8) = *(const short8*)(og + (size_t)(row0+row)*CDIM + c8*8);
    *(short8*)(Bs + row*144 + c8*8) = *(const short8*)(wt + v*8);
  }
  __syncthreads();
  int w = t >> 6, lane = t & 63;
  int wm = (w & 1) * 64, wn = (w >> 1) * 64;
  int m = lane & 15, q4 = lane >> 4;
  floatx4 acc[4][4];
  #pragma unroll
  for (int mi = 0; mi < 4; mi++)
    #pragma unroll
    for (int ni = 0; ni < 4; ni++)
      acc[mi][ni] = (floatx4){0.f, 0.f, 0.f, 0.f};
  #pragma unroll
  for (int k0 = 0; k0 < 128; k0 += 32){
    int koff = k0 + q4*8;
    short8 af[4], bf[4];
    #pragma unroll
    for (int mi = 0; mi < 4; mi++) af[mi] = *(const short8*)(As + (wm + mi*16 + m)*144 + koff);
    #pragma unroll
    for (int ni = 0; ni < 4; ni++) bf[ni] = *(const short8*)(Bs + (wn + ni*16 + m)*144 + koff);
    #pragma unroll
    for (int mi = 0; mi < 4; mi++)
      #pragma unroll
      for (int ni = 0; ni < 4; ni++)
        acc[mi][ni] = __builtin_amdgcn_mfma_f32_16x16x32_bf16(af[mi], bf[ni], acc[mi][ni], 0, 0, 0);
  }
  #pragma unroll
  for (int mi = 0; mi < 4; mi++)
    #pragma unroll
    for (int ni = 0; ni < 4; ni++){
      int col = wn + ni*16 + m;
      float bv = bo[col];
      #pragma unroll
      for (int r = 0; r < 4; r++){
        int orow = wm + mi*16 + q4*4 + r;
        out[(size_t)(row0+orow)*CDIM + col] = acc[mi][ni][r] + bv;
      }
    }
}

// ---------------- MFMA attention per (i,h) ----------------
// 256 threads = 4 waves; wave w owns Q-rows [w*96, w*96+96).
// Scores computed in exp2 domain (q pre-scaled, tri pre-scaled, mask scaled here).
// Softmax denominator via MFMA with all-ones B fragment (same C-layout as O).
#define VT_STRIDE 392
#define P_STRIDE  40
__global__ __launch_bounds__(256, 2) void attn_kernel(
    const ushort_t* __restrict__ qb, const ushort_t* __restrict__ kb,
    const ushort_t* __restrict__ vb, const ushort_t* __restrict__ gb,
    const float* __restrict__ mask, const float* __restrict__ trip2,
    ushort_t* __restrict__ og)
{
  __shared__ __align__(16) ushort_t Ks[JDIM*32];          // 24576 B
  __shared__ __align__(16) ushort_t Vt[32*VT_STRIDE];     // 25088 B
  __shared__ __align__(16) ushort_t Pb[4*96*P_STRIDE];    // 30720 B
  int i = blockIdx.x, h = blockIdx.y;
  int t = threadIdx.x;
  size_t rbase = (size_t)i * JDIM;

  // stage K natural, V transposed with within-block32 column permutation:
  // actual col j = blk*32 + sub*16 + m  ->  stored pos blk*32 + m*2 + sub
  for (int idx = t; idx < JDIM*4; idx += 256){
    int j = idx >> 2, c8 = idx & 3;
    *(short8*)(Ks + j*32 + c8*8) = *(const short8*)(kb + (rbase + j)*CDIM + h*DHD + c8*8);
    short8 v8 = *(const short8*)(vb + (rbase + j)*CDIM + h*DHD + c8*8);
    int jb = j & 31;
    int jp = (j & ~31) | (((jb & 15) << 1) | (jb >> 4));
    #pragma unroll
    for (int e = 0; e < 8; e++) Vt[(c8*8 + e)*VT_STRIDE + jp] = (unsigned short)v8[e];
  }
  __syncthreads();

  int w = t >> 6, lane = t & 63;
  int m = lane & 15, q4 = lane >> 4;
  int wm = w * 96;
  ushort_t* Pw = Pb + w * 96 * P_STRIDE;

  short8 qf[6];
  #pragma unroll
  for (int t6 = 0; t6 < 6; t6++)
    qf[t6] = *(const short8*)(qb + (rbase + wm + t6*16 + m)*CDIM + h*DHD + q4*8);

  const short8 ones = (short8){0x3F80,0x3F80,0x3F80,0x3F80,0x3F80,0x3F80,0x3F80,0x3F80};
  floatx4 oacc[6][2];
  floatx4 lacc[6];
  #pragma unroll
  for (int t6 = 0; t6 < 6; t6++){
    oacc[t6][0] = (floatx4){0.f,0.f,0.f,0.f};
    oacc[t6][1] = (floatx4){0.f,0.f,0.f,0.f};
    lacc[t6]    = (floatx4){0.f,0.f,0.f,0.f};
  }

  const float* triph = trip2 + (size_t)h * NPOS;

  for (int kbk = 0; kbk < 12; kbk++){
    int col0 = kbk * 32;
    short8 kf0 = *(const short8*)(Ks + (col0 + m)*32 + q4*8);
    short8 kf1 = *(const short8*)(Ks + (col0 + 16 + m)*32 + q4*8);
    float mb0 = (1e9f*LOG2E) * (mask[rbase + col0 + m] - 1.0f);
    float mb1 = (1e9f*LOG2E) * (mask[rbase + col0 + 16 + m] - 1.0f);

    #pragma unroll
    for (int t6 = 0; t6 < 6; t6++){
      floatx4 z = (floatx4){0.f,0.f,0.f,0.f};
      floatx4 s0 = __builtin_amdgcn_mfma_f32_16x16x32_bf16(qf[t6], kf0, z, 0, 0, 0);
      floatx4 s1 = __builtin_amdgcn_mfma_f32_16x16x32_bf16(qf[t6], kf1, z, 0, 0, 0);
      int qrow = wm + t6*16 + q4*4;
      const float* trow = triph + (size_t)qrow*JDIM + col0 + m*2;  // permuted pairs
      #pragma unroll
      for (int r = 0; r < 4; r++){
        float2 t2 = *(const float2*)(trow + r*JDIM);
        float p0 = EXP2F(s0[r] + mb0 + t2.x);
        float p1 = EXP2F(s1[r] + mb1 + t2.y);
        *(unsigned int*)(Pw + (t6*16 + q4*4 + r)*P_STRIDE + m*2) = pack2bf(p0, p1);
      }
    }
    // PV + denominator: A = P (permuted k), B = Vt (same permutation) / ones
    short8 vf0 = *(const short8*)(Vt + m*VT_STRIDE + col0 + q4*8);
    short8 vf1 = *(const short8*)(Vt + (16 + m)*VT_STRIDE + col0 + q4*8);
    #pragma unroll
    for (int t6 = 0; t6 < 6; t6++){
      short8 pf = *(const short8*)(Pw + (t6*16 + m)*P_STRIDE + q4*8);
      oacc[t6][0] = __builtin_amdgcn_mfma_f32_16x16x32_bf16(pf, vf0, oacc[t6][0], 0, 0, 0);
      oacc[t6][1] = __builtin_amdgcn_mfma_f32_16x16x32_bf16(pf, vf1, oacc[t6][1], 0, 0, 0);
      lacc[t6]    = __builtin_amdgcn_mfma_f32_16x16x32_bf16(pf, ones, lacc[t6], 0, 0, 0);
    }
  }

  // epilogue: o = acc * (1/l) * g   (lacc C-layout rows == oacc rows)
  #pragma unroll
  for (int t6 = 0; t6 < 6; t6++){
    int qrow = wm + t6*16 + q4*4;
    #pragma unroll
    for (int r = 0; r < 4; r++){
      float rl = 1.0f / (lacc[t6][r] + 1e-30f);
      #pragma unroll
      for (int dt = 0; dt < 2; dt++){
        size_t oidx = (rbase + qrow + r)*CDIM + h*DHD + dt*16 + m;
        float o = oacc[t6][dt][r] * rl * bf2f(gb[oidx]);
        og[oidx] = f2bf(o);
      }
    }
  }
}

extern "C" void kernel_launch(void* const* d_in, const int* in_sizes, int n_in,
                              void* d_out, int out_size, void* d_ws, size_t ws_size,
                              hipStream_t stream)
{
  const float* x    = (const float*)d_in[0];
  const float* mask = (const float*)d_in[1];
  const float* lnw  = (const float*)d_in[2];
  const float* lnb  = (const float*)d_in[3];
  const float* wtri = (const float*)d_in[4];
  const float* wq   = (const float*)d_in[5];
  const float* wk   = (const float*)d_in[6];
  const float* wv   = (const float*)d_in[7];
  const float* wg   = (const float*)d_in[8];
  const float* bg   = (const float*)d_in[9];
  const float* wo   = (const float*)d_in[10];
  const float* bo   = (const float*)d_in[11];

  char* ws = (char*)d_ws;
  const size_t SZ = (size_t)NPOS * CDIM * 2;     // 37,748,736 B per [N,128] bf16
  ushort_t* qb  = (ushort_t*)(ws);
  ushort_t* kbp = (ushort_t*)(ws + 1*SZ);
  ushort_t* vbp = (ushort_t*)(ws + 2*SZ);
  ushort_t* gbp = (ushort_t*)(ws + 3*SZ);
  ushort_t* og  = (ushort_t*)(ws + 4*SZ);
  ushort_t* wt  = (ushort_t*)(ws + 5*SZ);        // 5 * 128*128 bf16 = 160 KB
  float*    tri = (float*)(ws + 5*SZ + 5*16384*2);

  wt_kernel<<<320, 256, 0, stream>>>(wq, wk, wv, wg, wo, wt);
  proj_fused_kernel<<<dim3(NPOS/128, 4), 256, 0, stream>>>(
      x, lnw, lnb, wtri, wt, qb, bg, tri);
  attn_kernel<<<dim3(JDIM, HNUM), 256, 0, stream>>>(qb, kbp, vbp, gbp, mask, tri, og);
  out_gemm_kernel<<<NPOS/128, 256, 0, stream>>>(og, wt + 4*16384, (float*)d_out, bo);
}